// Round 18
// baseline (278.454 us; speedup 1.0000x reference)
//
#include <hip/hip_runtime.h>

#define N_NODES 50000
#define E_EDGES 800000
#define M_ROWS  12500
#define IN_DIM  256
#define HID     128
#define OUT_DIM 64
#define EPS     1e-5f
#define SLOPE   0.1f
#define SB_BITS 9
#define SB_SIZE 512
#define NSB     196         // ceil(2N / 512) super-buckets
#define SB_CAP  (12 * 1024) // mean 8192, sigma~90 -> 45 sigma; fixed inputs safe

typedef unsigned short u16;
typedef unsigned int u32;
typedef unsigned char u8;
typedef __attribute__((ext_vector_type(8))) short short8;
typedef __attribute__((ext_vector_type(4))) float f32x4;
typedef __attribute__((ext_vector_type(2))) float f32x2;
typedef __attribute__((ext_vector_type(2))) unsigned int u32x2;

__device__ __forceinline__ float leaky_f(float x) { return x >= 0.f ? x : SLOPE * x; }

__device__ __forceinline__ u16 f2bf(float f) {
  u32 x = __float_as_uint(f);
  return (u16)((x + 0x7fffu + ((x >> 16) & 1u)) >> 16);
}
__device__ __forceinline__ float bf2f(u16 u) { return __uint_as_float((u32)u << 16); }

// f32 -> OCP e4m3fn, RNE. Max finite 448 (0x7E); clamps NaN/overflow to 448.
__device__ __forceinline__ u8 f2fp8(float f) {
  u32 x = __float_as_uint(f);
  u32 sgn = (x >> 24) & 0x80u;
  u32 ax = x & 0x7fffffffu;
  if (ax > 0x43e00000u) ax = 0x43e00000u;     // clamp |f| to 448
  u32 code;
  if (ax < 0x3c800000u) {                     // |f| < 2^-6: subnormal (n * 2^-9)
    code = (u32)(__uint_as_float(ax) * 512.0f + 0.5f);
  } else {
    u32 rr = ax + 0x7ffffu + ((ax >> 20) & 1u);  // RNE at bit 20
    code = (rr >> 20) - 960u;                    // (e32<<3|m3) - (120<<3)
    if (code > 0x7eu) code = 0x7eu;
  }
  return (u8)(sgn | code);
}

#if defined(__has_builtin)
#if __has_builtin(__builtin_amdgcn_cvt_pk_f32_fp8)
#define HAVE_CVT_FP8 1
#endif
#if __has_builtin(__builtin_amdgcn_cvt_pk_fp8_f32)
#define HAVE_CVT_FP8PK 1
#endif
#endif

#ifdef HAVE_CVT_FP8
template <bool HI>
__device__ __forceinline__ f32x2 fp8pair(u32 w) {
  return __builtin_amdgcn_cvt_pk_f32_fp8((int)w, HI);  // HI is constexpr
}
#else
__device__ __forceinline__ float fp8one(u32 b) {
  u32 em = b & 0x7fu;
  float m = (em >= 8u) ? __uint_as_float((((em >> 3) + 120u) << 23) | ((em & 7u) << 20))
                       : (float)em * (1.f / 512.f);
  return (b & 0x80u) ? -m : m;
}
template <bool HI>
__device__ __forceinline__ f32x2 fp8pair(u32 w) {
  u32 s = HI ? 16 : 0;
  f32x2 r;
  r.x = fp8one((w >> s) & 0xffu);
  r.y = fp8one((w >> (s + 8)) & 0xffu);
  return r;
}
#endif

// pack 2 f32 -> 2 fp8 bytes (low 16 bits). HW packed cvt where available.
__device__ __forceinline__ u32 fp8pk2(float a, float b) {
#ifdef HAVE_CVT_FP8PK
  return ((u32)__builtin_amdgcn_cvt_pk_fp8_f32(a, b, 0, false)) & 0xffffu;
#else
  return (u32)f2fp8(a) | ((u32)f2fp8(b) << 8);
#endif
}

// 8 fp8 (u32x2) -> 8 bf16. LOSSLESS: e4m3 subset of bf16.
__device__ __forceinline__ short8 fp8x8_bf16(u32x2 v) {
  f32x2 p0 = fp8pair<false>(v.x), p1 = fp8pair<true>(v.x);
  f32x2 p2 = fp8pair<false>(v.y), p3 = fp8pair<true>(v.y);
  short8 s;
  s[0] = (short)f2bf(p0.x); s[1] = (short)f2bf(p0.y);
  s[2] = (short)f2bf(p1.x); s[3] = (short)f2bf(p1.y);
  s[4] = (short)f2bf(p2.x); s[5] = (short)f2bf(p2.y);
  s[6] = (short)f2bf(p3.x); s[7] = (short)f2bf(p3.y);
  return s;
}

struct GArgs {
  const void* A1[2];
  const void* A2[2];
  const u16* Bt[2];
  const u16* Bt2[2];    // Wp (fused pool), MODE 3 only
  const float* bias[2];
  const float* bias2[2];// bp (fused pool)
  u8* h8[2];            // fp8 e4m3 activation storage (the ONLY h)
  float* bnsum[2];
  float* bnss[2];
  const int* seg[2];
  const int* cnt[2];
  float* y[2];
};

struct EdgeArgs {
  const int* src[2];
  const int* dst[2];
  const int* seg[2];
};

struct CvtArgs {
  const float* W[12];
  u16* Bt;
};

// ---------------------------------------------------------------------------
// R17-proven streaming MFMA GEMM (278.3us) + persistent-B 2-tile blocks (R18).
// R17 forensics: layer FETCH 50.7MB while fp8 A is only 25.6MB -- the rest is
// the B-tile HBM refetch (782 blocks x 64KB), now the dominant stream AND the
// per-block latency wall. Fix: MODE 0/1 use HALF the grid; each block does 2
// row-tiles (b, b+gridDim.x) with B staged into LDS ONCE. Tile-1 prologue is
// just the A-register wall (no barrier: LDS B read-only after first sync).
// Halves B walls + B traffic. MODE 3 stays 1-tile (fused epilogue reuses Bs).
// MODE 0 ENCODE: A1 = f32, K in 2 halves; writes ONLY h8; BN stats span tiles.
// MODE 1 LAYER0: A1 = fp8 h8, A2 = fp8 agg8; writes ONLY h8.
// MODE 3 LAYER1+POOL: A1/A2 fp8; fused v@Wp + pool atomics.
// ---------------------------------------------------------------------------
template <int BN, int MODE, int KTOT>
__global__ __launch_bounds__(512, 4) void gemm_stream(GArgs ga, int nrows) {
  constexpr int NI = BN / 16;
  constexpr int KT = KTOT / 32;
  constexpr int LDK = KTOT + 8;                 // pad 8 u16 = 16B
  constexpr int BEL = BN * KTOT;                // B elements
  constexpr int SIT = BEL / (512 * 8);          // staging iters
  constexpr int KSH = (KTOT == 256) ? 8 : 7;
  constexpr int NTILES = (MODE == 3) ? 1 : 2;
  __shared__ u16 Bs[BN * LDK];
  __shared__ float redS[(MODE == 0) ? 128 : 1];
  __shared__ float redQ[(MODE == 0) ? 128 : 1];

  const int pb = blockIdx.y;
  const int t = threadIdx.x;
  const int w = t >> 6, lane = t & 63;
  const int laneM = lane & 15, kg = lane >> 4;

  const u16* Bt = ga.Bt[pb];
  const float* bias = ga.bias[pb];

  float bcol[NI];
#pragma unroll
  for (int ni = 0; ni < NI; ni++) bcol[ni] = bias[ni * 16 + laneM];

  float ssum[NI], ssq[NI];
#pragma unroll
  for (int ni = 0; ni < NI; ni++) { ssum[ni] = 0.f; ssq[ni] = 0.f; }
  if constexpr (MODE == 0) {
    if (t < 128) { redS[t] = 0.f; redQ[t] = 0.f; }
  }

  int m0_last = 0;  // for MODE 3 epilogue (single tile)

  for (int tt = 0; tt < NTILES; tt++) {
    const int m0 = (blockIdx.x + tt * gridDim.x) * 128;
    if (m0 >= nrows) break;   // uniform per block
    m0_last = m0;
    const int r0 = m0 + w * 16;
    int ra = r0 + laneM;
    if (ra >= nrows) ra = nrows - 1;

    short8 sreg[SIT];
    short8 af[KT];

    if constexpr (MODE == 0) {
      const float* A = (const float*)ga.A1[pb] + (size_t)ra * KTOT + kg * 8;
      float4 pf[8];
      if (tt == 0) {
#pragma unroll
        for (int si = 0; si < SIT; si++)
          sreg[si] = *(const short8*)(Bt + si * 4096 + t * 8);
      }
#pragma unroll
      for (int kt = 0; kt < 4; kt++) {
        pf[2 * kt] = *(const float4*)(A + kt * 32);
        pf[2 * kt + 1] = *(const float4*)(A + kt * 32 + 4);
      }
      __builtin_amdgcn_sched_barrier(0);
#pragma unroll
      for (int kt = 0; kt < 4; kt++) {
        float4 v0 = pf[2 * kt], v1 = pf[2 * kt + 1];
        short8 s;
        s[0] = (short)f2bf(v0.x); s[1] = (short)f2bf(v0.y);
        s[2] = (short)f2bf(v0.z); s[3] = (short)f2bf(v0.w);
        s[4] = (short)f2bf(v1.x); s[5] = (short)f2bf(v1.y);
        s[6] = (short)f2bf(v1.z); s[7] = (short)f2bf(v1.w);
        af[kt] = s;
      }
      if (tt == 0) {
#pragma unroll
        for (int si = 0; si < SIT; si++) {
          int i = si * 4096 + t * 8;
          *(short8*)&Bs[(i >> KSH) * LDK + (i & (KTOT - 1))] = sreg[si];
        }
      }
#pragma unroll
      for (int kt = 0; kt < 4; kt++) {
        pf[2 * kt] = *(const float4*)(A + 128 + kt * 32);
        pf[2 * kt + 1] = *(const float4*)(A + 128 + kt * 32 + 4);
      }
      __builtin_amdgcn_sched_barrier(0);
#pragma unroll
      for (int kt = 0; kt < 4; kt++) {
        float4 v0 = pf[2 * kt], v1 = pf[2 * kt + 1];
        short8 s;
        s[0] = (short)f2bf(v0.x); s[1] = (short)f2bf(v0.y);
        s[2] = (short)f2bf(v0.z); s[3] = (short)f2bf(v0.w);
        s[4] = (short)f2bf(v1.x); s[5] = (short)f2bf(v1.y);
        s[6] = (short)f2bf(v1.z); s[7] = (short)f2bf(v1.w);
        af[4 + kt] = s;
      }
    } else {
      if (tt == 0) {
#pragma unroll
        for (int si = 0; si < SIT; si++)
          sreg[si] = *(const short8*)(Bt + si * 4096 + t * 8);
      }
      const u8* A1 = (const u8*)ga.A1[pb] + (size_t)ra * HID + kg * 8;
      const u8* A2 = (const u8*)ga.A2[pb] + (size_t)ra * HID + kg * 8;
      u32x2 a8[8];
#pragma unroll
      for (int kt = 0; kt < 4; kt++) a8[kt] = *(const u32x2*)(A1 + kt * 32);
#pragma unroll
      for (int kt = 0; kt < 4; kt++) a8[4 + kt] = *(const u32x2*)(A2 + kt * 32);
      __builtin_amdgcn_sched_barrier(0);
#pragma unroll
      for (int kt = 0; kt < 8; kt++) af[kt] = fp8x8_bf16(a8[kt]);
      if (tt == 0) {
#pragma unroll
        for (int si = 0; si < SIT; si++) {
          int i = si * 4096 + t * 8;
          *(short8*)&Bs[(i >> KSH) * LDK + (i & (KTOT - 1))] = sreg[si];
        }
      }
    }
    if (tt == 0) __syncthreads();  // B visible; later tiles: B read-only

    // ---- steady state: pure LDS + MFMA ----
    f32x4 acc[NI];
#pragma unroll
    for (int ni = 0; ni < NI; ni++) acc[ni] = (f32x4){0.f, 0.f, 0.f, 0.f};

#pragma unroll
    for (int kt = 0; kt < KT; kt++) {
      const int k0 = kt * 32 + kg * 8;
      short8 a = af[kt];
#pragma unroll
      for (int ni = 0; ni < NI; ni++) {
        short8 b = *(const short8*)&Bs[(ni * 16 + laneM) * LDK + k0];
        acc[ni] = __builtin_amdgcn_mfma_f32_16x16x32_bf16(a, b, acc[ni], 0, 0, 0);
      }
    }

    if constexpr (MODE == 3) {
      // ---- fused projection + mean-pool (destroys Bs; single-tile mode) ----
      u16* Vt = Bs;                   // [128][136] bf16 v-tile
      u16* Wpt = Bs + 128 * 136;      // [64][136] bf16 Wp
      const u16* Bt2 = ga.Bt2[pb];
      short8 wp[2];
      {
        int i0 = t * 2;               // 1024 short8s of Wp, 2 per thread
        wp[0] = *(const short8*)(Bt2 + (size_t)i0 * 8);
        wp[1] = *(const short8*)(Bt2 + (size_t)(i0 + 1) * 8);
      }
      __syncthreads();                // all waves done reading Bs (W1)
#pragma unroll
      for (int r = 0; r < 4; r++) {
        int lrow = w * 16 + kg * 4 + r;
#pragma unroll
        for (int ni = 0; ni < NI; ni++) {
          float v = leaky_f(acc[ni][r] + bcol[ni]);
          Vt[lrow * 136 + ni * 16 + laneM] = f2bf(v);
        }
      }
      {
        int i0 = t * 2;
#pragma unroll
        for (int q = 0; q < 2; q++) {
          int i = i0 + q;
          *(short8*)&Wpt[(i >> 4) * 136 + (i & 15) * 8] = wp[q];
        }
      }
      __syncthreads();
      f32x4 acc2[4];
#pragma unroll
      for (int n2 = 0; n2 < 4; n2++) acc2[n2] = (f32x4){0.f, 0.f, 0.f, 0.f};
#pragma unroll
      for (int kt = 0; kt < 4; kt++) {
        int k0 = kt * 32 + kg * 8;
        short8 a2 = *(const short8*)&Vt[(w * 16 + laneM) * 136 + k0];
#pragma unroll
        for (int n2 = 0; n2 < 4; n2++) {
          short8 b2 = *(const short8*)&Wpt[(n2 * 16 + laneM) * 136 + k0];
          acc2[n2] = __builtin_amdgcn_mfma_f32_16x16x32_bf16(a2, b2, acc2[n2], 0, 0, 0);
        }
      }
      const float* bp2 = ga.bias2[pb];
#pragma unroll
      for (int r = 0; r < 4; r++) {
        int gr = m0_last + w * 16 + kg * 4 + r;
        if (gr >= nrows) continue;
        int sI = ga.seg[pb][gr];
        int cv = ga.cnt[pb][sI];
        float pw = 1.f / (float)(cv > 1 ? cv : 1);
#pragma unroll
        for (int n2 = 0; n2 < 4; n2++) {
          int col = n2 * 16 + laneM;
          float v = acc2[n2][r] + bp2[col];
          atomicAdd(&ga.y[pb][(size_t)sI * OUT_DIM + col], v * pw);
        }
      }
      return;
    }

    // ---- MODE 0/1 per-tile epilogue: fp8 h8 write (+ BN stat accumulate) ----
#pragma unroll
    for (int r = 0; r < 4; r++) {
      int gr = r0 + kg * 4 + r;
      if (gr >= nrows) continue;
      float vv[NI];
#pragma unroll
      for (int ni = 0; ni < NI; ni++) {
        float v = leaky_f(acc[ni][r] + bcol[ni]);
        vv[ni] = v;
        if constexpr (MODE == 0) { ssum[ni] += v; ssq[ni] += v * v; }
      }
      u8* hrow = ga.h8[pb] + (size_t)gr * BN + laneM;
#pragma unroll
      for (int ni = 0; ni < NI; ni += 2) {
        u32 pk = fp8pk2(vv[ni], vv[ni + 1]);
        hrow[ni * 16] = (u8)pk;
        hrow[(ni + 1) * 16] = (u8)(pk >> 8);
      }
    }
  }

  if constexpr (MODE == 0) {
#pragma unroll
    for (int ni = 0; ni < NI; ni++) {
      float a = ssum[ni], b = ssq[ni];
      a += __shfl_xor(a, 16); a += __shfl_xor(a, 32);
      b += __shfl_xor(b, 16); b += __shfl_xor(b, 32);
      if (kg == 0) {
        atomicAdd(&redS[ni * 16 + laneM], a);
        atomicAdd(&redQ[ni * 16 + laneM], b);
      }
    }
    __syncthreads();
    if (t < 128) {
      atomicAdd(&ga.bnsum[pb][t], redS[t]);
      atomicAdd(&ga.bnss[pb][t], redQ[t]);
    }
  }
}

// Weights -> bf16 transposed Bt[n][k]; SKIPS Bt0 (folded later with BN affine).
__global__ __launch_bounds__(256) void cvt_weightsA(CvtArgs a) {
  int i = blockIdx.x * 256 + threadIdx.x;
  if (i >= 2 * 106496) return;
  int p = i >= 106496;
  int j = i - p * 106496;
  const float* const* W = a.W + p * 6;
  u16* out = a.Bt + (size_t)p * 106496;
  if (j < 32768) {
    int n = j >> 8, k = j & 255;
    out[j] = f2bf(W[0][k * 128 + n]);
  } else if (j < 65536) {
    return;
  } else if (j < 98304) {
    int q = j - 65536, n = q >> 8, k = q & 255;
    out[j] = f2bf(k < 128 ? W[3][k * 128 + n] : W[4][(k - 128) * 128 + n]);
  } else {
    int q = j - 98304, n = q >> 7, k = q & 127;
    out[j] = f2bf(W[5][k * 64 + n]);
  }
}

// abc layout: a[256] | c[256] | nc[256] | bias0p[256]
__global__ void bn_final(const float* __restrict__ bnstat,
                         const float* __restrict__ g0, const float* __restrict__ b0,
                         const float* __restrict__ g1, const float* __restrict__ b1,
                         float* __restrict__ abc) {
  int t = threadIdx.x;  // 256
  int p = t >> 7, cix = t & 127;
  const float* bs = bnstat + p * 256;
  float mu = bs[cix] * (1.f / N_NODES);
  float var = bs[128 + cix] * (1.f / N_NODES) - mu * mu;
  float rs = rsqrtf(var + EPS);
  const float* g = p ? g1 : g0;
  const float* b = p ? b1 : b0;
  float av = g[cix] * rs;
  float cv = b[cix] - mu * av;
  abc[t] = av;
  abc[256 + t] = cv;
  abc[512 + t] = (av != 0.f) ? (-cv / av) : 0.f;
}

// Fold BN affine into layer-0 weights.
__global__ __launch_bounds__(256) void cvt_fold(
    const float* __restrict__ Wl0_0, const float* __restrict__ Wr0_0,
    const float* __restrict__ Wl0_1, const float* __restrict__ Wr0_1,
    const float* __restrict__ b0_0, const float* __restrict__ b0_1,
    float* __restrict__ abc, u16* __restrict__ BtAll) {
  int i = blockIdx.x * 256 + threadIdx.x;
  if (i < 65536) {
    int p = i >> 15, q = i & 32767;
    int n = q >> 8, k = q & 255;
    const float* Wl = p ? Wl0_1 : Wl0_0;
    const float* Wr = p ? Wr0_1 : Wr0_0;
    float wv = (k < 128) ? Wl[k * 128 + n] : Wr[(k - 128) * 128 + n];
    float av = abc[p * 128 + (k & 127)];
    BtAll[(size_t)p * 106496 + 32768 + q] = f2bf(wv * av);
  } else if (i < 65536 + 256) {
    int j = i - 65536;
    int p = j >> 7, n = j & 127;
    const float* Wl = p ? Wl0_1 : Wl0_0;
    const float* Wr = p ? Wr0_1 : Wr0_0;
    const float* c = abc + 256 + p * 128;
    float s = (p ? b0_1 : b0_0)[n];
    for (int k = 0; k < 128; k++) s += c[k] * (Wl[k * 128 + n] + Wr[k * 128 + n]);
    abc[768 + j] = s;
  }
}

// pooling counts
__global__ void cnt_count(EdgeArgs ea, int* __restrict__ cnt) {
  int i = blockIdx.x * blockDim.x + threadIdx.x;
  if (i < 2 * N_NODES) {
    int p = i >= N_NODES;
    int k = i - p * N_NODES;
    atomicAdd(&cnt[p * M_ROWS + ea.seg[p][k]], 1);
  }
}

// --------- Phase A: partition edges into NSB super-buckets ------------------
// packed: dst_local(9b) << 17 | src(16b). Tile = 2048 edges, block-local
// counting sort, wave-per-bucket chunk copy-out.
__global__ __launch_bounds__(256) void part_edges(EdgeArgs ea, u32* __restrict__ sbuf,
                                                  int* __restrict__ gcursor) {
  __shared__ u32 lpack[2048];
  __shared__ int hist[NSB], base[NSB], gbase[NSB], lofs[NSB];
  int t = threadIdx.x;
  int e0 = blockIdx.x * 2048;
  for (int i = t; i < NSB; i += 256) hist[i] = 0;
  __syncthreads();
  u32 myp[8];
  int myb[8];
#pragma unroll
  for (int q = 0; q < 8; q++) {
    int i = e0 + q * 256 + t;
    int b = -1;
    u32 pk = 0;
    if (i < 2 * E_EDGES) {
      int p = i >= E_EDGES;
      int j = i - p * E_EDGES;
      int d = p * N_NODES + ea.dst[p][j];
      int s = ea.src[p][j];
      b = d >> SB_BITS;
      pk = ((u32)(d & (SB_SIZE - 1)) << 17) | (u32)s;
      atomicAdd(&hist[b], 1);
    }
    myb[q] = b;
    myp[q] = pk;
  }
  __syncthreads();
  if (t == 0) {
    int acc = 0;
    for (int b = 0; b < NSB; b++) { base[b] = acc; acc += hist[b]; }
  }
  __syncthreads();
  for (int i = t; i < NSB; i += 256) {
    lofs[i] = 0;
    gbase[i] = atomicAdd(&gcursor[i], hist[i]);
  }
  __syncthreads();
#pragma unroll
  for (int q = 0; q < 8; q++) {
    if (myb[q] >= 0) {
      int pos = atomicAdd(&lofs[myb[q]], 1);
      lpack[base[myb[q]] + pos] = myp[q];
    }
  }
  __syncthreads();
  int wid = t >> 6, lane = t & 63;
  for (int b = wid; b < NSB; b += 4) {
    int n = hist[b], lb = base[b], gb = gbase[b];
    for (int k = lane; k < n; k += 64)
      sbuf[(size_t)b * SB_CAP + gb + k] = lpack[lb + k];
  }
}

// --------- Phase B: per-super-bucket CSR build (one block per bucket) -------
// 196 blocks x 512 threads; 512-node buckets -> ~8K edges/block.
__global__ __launch_bounds__(512) void build_csr(
    const u32* __restrict__ sbuf, const int* __restrict__ gtot,
    int* __restrict__ offs, float* __restrict__ dinv, u16* __restrict__ colu) {
  __shared__ int ldeg[SB_SIZE];
  __shared__ int lcur[SB_SIZE];
  __shared__ int wsum[8];
  __shared__ int sbase_s;
  int b = blockIdx.x, t = threadIdx.x;
  int lane = t & 63, wid = t >> 6;
  ldeg[t] = 0;
  if (t < 64) {
    // edge_base = sum of gtot[0..b) via 64-lane masked sum + butterfly
    int s = 0;
    for (int i = lane; i < b; i += 64) s += gtot[i];
#pragma unroll
    for (int off = 1; off < 64; off <<= 1) s += __shfl_xor(s, off, 64);
    if (lane == 0) sbase_s = s;
  }
  __syncthreads();
  const int cnt = gtot[b];
  const int edge_base = sbase_s;
  const int node0 = b << SB_BITS;
  int nend = 2 * N_NODES - node0;
  if (nend > SB_SIZE) nend = SB_SIZE;
  const u32* me = sbuf + (size_t)b * SB_CAP;
  for (int k = t; k < cnt; k += 512) atomicAdd(&ldeg[me[k] >> 17], 1);
  __syncthreads();
  // block scan over 512 (one node per thread)
  int d = ldeg[t];
  int incl = d;
#pragma unroll
  for (int off = 1; off < 64; off <<= 1) {
    int u = __shfl_up(incl, off, 64);
    if (lane >= off) incl += u;
  }
  if (lane == 63) wsum[wid] = incl;
  __syncthreads();
  if (t == 0) {
    int acc = 0;
#pragma unroll
    for (int i = 0; i < 8; i++) { int v = wsum[i]; wsum[i] = acc; acc += v; }
  }
  __syncthreads();
  int ex = wsum[wid] + incl - d;
  if (t < nend) {
    offs[node0 + t] = edge_base + ex;
    dinv[node0 + t] = d > 0 ? 1.f / (float)d : -1.f;
  }
  lcur[t] = ex;
  __syncthreads();
  for (int k = t; k < cnt; k += 512) {
    u32 v = me[k];
    int pos = atomicAdd(&lcur[v >> 17], 1);
    colu[edge_base + pos] = (u16)(v & 0xFFFFu);
  }
  if (b == 0 && t == 0) offs[2 * N_NODES] = 2 * E_EDGES;
}

// --------- mean-aggregate: fp8 gather, fp8 output ---------------------------
// 1 wave/node, 4 edge-groups x 16 col-lanes; lane loads uint2 (8B = 8 fp8
// cols, 2 lines/edge) -- the empirically optimal shape. Output agg8 fp8 via
// packed cvt (R12-validated). dinv<0 marks deg==0 -> nc[col] (f32).
__global__ __launch_bounds__(256) void aggregate_fp8(
    const u8* __restrict__ h8, const u16* __restrict__ colu,
    const int* __restrict__ offs, const float* __restrict__ dinv,
    const float* __restrict__ nc, u8* __restrict__ agg) {
  int gw = (blockIdx.x * 256 + threadIdx.x) >> 6;
  int lane = threadIdx.x & 63;
  if (gw >= 2 * N_NODES) return;
  int panel = gw >= N_NODES;
  const uint2* hp = (const uint2*)(h8 + (size_t)panel * N_NODES * 128);
  int grp = lane >> 4, li = lane & 15;
  int s = offs[gw], e = offs[gw + 1];
  float a[8];
#pragma unroll
  for (int k = 0; k < 8; k++) a[k] = 0.f;

  auto acc8 = [&](uint2 v) {
    f32x2 p0 = fp8pair<false>(v.x);
    f32x2 p1 = fp8pair<true>(v.x);
    f32x2 p2 = fp8pair<false>(v.y);
    f32x2 p3 = fp8pair<true>(v.y);
    a[0] += p0.x; a[1] += p0.y; a[2] += p1.x; a[3] += p1.y;
    a[4] += p2.x; a[5] += p2.y; a[6] += p3.x; a[7] += p3.y;
  };

  int j = s;
  for (; j + 16 <= e; j += 16) {
    int c0 = colu[j + grp];
    int c1 = colu[j + 4 + grp];
    int c2 = colu[j + 8 + grp];
    int c3 = colu[j + 12 + grp];
    uint2 v0 = hp[(size_t)c0 * 16 + li];
    uint2 v1 = hp[(size_t)c1 * 16 + li];
    uint2 v2 = hp[(size_t)c2 * 16 + li];
    uint2 v3 = hp[(size_t)c3 * 16 + li];
    acc8(v0); acc8(v1); acc8(v2); acc8(v3);
  }
  for (; j + 4 <= e; j += 4) {
    int c = colu[j + grp];
    uint2 v = hp[(size_t)c * 16 + li];
    acc8(v);
  }
  if (j + grp < e) {
    int c = colu[j + grp];
    uint2 v = hp[(size_t)c * 16 + li];
    acc8(v);
  }

#pragma unroll
  for (int k = 0; k < 8; k++) {
    a[k] += __shfl_xor(a[k], 16);
    a[k] += __shfl_xor(a[k], 32);
  }

  if (grp == 0) {
    float di = dinv[gw];
    float o[8];
    if (di < 0.f) {
      const float* np = nc + panel * 128 + li * 8;
#pragma unroll
      for (int k = 0; k < 8; k++) o[k] = np[k];
    } else {
#pragma unroll
      for (int k = 0; k < 8; k++) o[k] = a[k] * di;
    }
    uint2 ov;
    ov.x = fp8pk2(o[0], o[1]) | (fp8pk2(o[2], o[3]) << 16);
    ov.y = fp8pk2(o[4], o[5]) | (fp8pk2(o[6], o[7]) << 16);
    ((uint2*)agg)[(size_t)gw * 16 + li] = ov;
  }
}

__global__ __launch_bounds__(256) void mse_kernel(const float* __restrict__ yb,
                                                  const float* __restrict__ x0,
                                                  const float* __restrict__ x1,
                                                  float* __restrict__ acc) {
  __shared__ float ls[256];
  int pb = blockIdx.y;
  const float* y = yb + (size_t)pb * M_ROWS * OUT_DIM;
  const float* x = pb ? x1 : x0;
  float s = 0.f;
  for (int i = blockIdx.x * 256 + threadIdx.x; i < M_ROWS * OUT_DIM; i += gridDim.x * 256) {
    float d = y[i] - x[i];
    s += d * d;
  }
  ls[threadIdx.x] = s;
  __syncthreads();
  for (int o = 128; o > 0; o >>= 1) {
    if (threadIdx.x < o) ls[threadIdx.x] += ls[threadIdx.x + o];
    __syncthreads();
  }
  if (threadIdx.x == 0) atomicAdd(&acc[pb], ls[0]);
}

__global__ void finalize(const float* __restrict__ acc, float* __restrict__ out) {
  int t = threadIdx.x;
  if (t < 2) out[t] = acc[t] * (1.f / (float)(M_ROWS * OUT_DIM));
}

// ---------------------------------------------------------------------------
extern "C" void kernel_launch(void* const* d_in, const int* in_sizes, int n_in,
                              void* d_out, int out_size, void* d_ws, size_t ws_size,
                              hipStream_t stream) {
  (void)in_sizes; (void)n_in; (void)out_size; (void)ws_size;
  const float* feat[2] = {(const float*)d_in[0], (const float*)d_in[1]};
  const float* xmat[2] = {(const float*)d_in[2], (const float*)d_in[3]};
  const int* esrc[2] = {(const int*)d_in[4], (const int*)d_in[6]};
  const int* edst[2] = {(const int*)d_in[5], (const int*)d_in[7]};
  const int* aseg[2] = {(const int*)d_in[8], (const int*)d_in[9]};

  struct P {
    const float *W_mlp, *b_mlp, *bn_g, *bn_b, *Wl0, *Wr0, *b0, *Wl1, *Wr1, *b1, *Wp, *bp;
  } prm[2];
  for (int p = 0; p < 2; p++) {
    int b = 10 + 12 * p;
    prm[p] = {(const float*)d_in[b + 0], (const float*)d_in[b + 1],
              (const float*)d_in[b + 2], (const float*)d_in[b + 3],
              (const float*)d_in[b + 4], (const float*)d_in[b + 5],
              (const float*)d_in[b + 6], (const float*)d_in[b + 7],
              (const float*)d_in[b + 8], (const float*)d_in[b + 9],
              (const float*)d_in[b + 10], (const float*)d_in[b + 11]};
  }

  char* w = (char*)d_ws;
  auto carve = [&](size_t bytes) -> char* {
    char* r = w;
    w += (bytes + 255) & ~(size_t)255;
    return r;
  };
  // ---- zeroed region (single memset) ----
  char* zbase = w;
  int* gcursor = (int*)carve(NSB * 4);
  int* cnt    = (int*)carve((size_t)2 * M_ROWS * 4);
  float* bnstat = (float*)carve(2 * 256 * 4);
  float* lossacc = (float*)carve(64 * 4);
  float* zerobuf = (float*)carve(256 * 4);
  float* yb   = (float*)carve((size_t)2 * M_ROWS * OUT_DIM * 4);
  size_t zbytes = (size_t)(w - zbase);
  // ---- non-zeroed ----
  u8* agg8  = (u8*)carve((size_t)2 * N_NODES * HID);       // fp8 agg (12.8MB)
  u32* sbuf = (u32*)agg8;  // aliased: sbuf (9.4MB) dead before first aggregate write
  u8* h8b   = (u8*)carve((size_t)2 * N_NODES * HID);       // fp8 h (only h storage)
  float* dinv = (float*)carve((size_t)2 * N_NODES * 4);
  float* abc = (float*)carve(1024 * 4);  // a|c|nc|bias0p
  int* offs = (int*)carve((size_t)(2 * N_NODES + 1) * 4);
  u16* colu = (u16*)carve((size_t)2 * E_EDGES * 2);
  u16* BtAll = (u16*)carve((size_t)2 * 106496 * 2);

  const int TWO_N = 2 * N_NODES;

  EdgeArgs ea;
  for (int p = 0; p < 2; p++) { ea.src[p] = esrc[p]; ea.dst[p] = edst[p]; ea.seg[p] = aseg[p]; }

  CvtArgs ca;
  for (int p = 0; p < 2; p++) {
    ca.W[p * 6 + 0] = prm[p].W_mlp; ca.W[p * 6 + 1] = prm[p].Wl0;
    ca.W[p * 6 + 2] = prm[p].Wr0;   ca.W[p * 6 + 3] = prm[p].Wl1;
    ca.W[p * 6 + 4] = prm[p].Wr1;   ca.W[p * 6 + 5] = prm[p].Wp;
  }
  ca.Bt = BtAll;

  auto mkga = [&](int mode) {
    GArgs g{};
    for (int p = 0; p < 2; p++) {
      u8* hp8 = h8b + (size_t)p * N_NODES * HID;
      u8* ap8 = agg8 + (size_t)p * N_NODES * HID;
      const u16* btp = BtAll + (size_t)p * 106496;
      g.h8[p] = hp8;
      g.bnsum[p] = bnstat + p * 256;
      g.bnss[p] = bnstat + p * 256 + 128;
      g.seg[p] = aseg[p];
      g.cnt[p] = cnt + p * M_ROWS;
      g.y[p] = yb + (size_t)p * M_ROWS * OUT_DIM;
      g.Bt2[p] = btp + 98304;
      g.bias2[p] = prm[p].bp;
      if (mode == 0) {
        g.A1[p] = feat[p];
        g.Bt[p] = btp;
        g.bias[p] = prm[p].b_mlp;
      } else if (mode == 1) {       // layer 0: A1 fp8 h8, A2 fp8 agg8
        g.A1[p] = hp8;
        g.A2[p] = ap8;
        g.Bt[p] = btp + 32768;
        g.bias[p] = (const float*)(abc + 768 + p * 128);
      } else {                      // layer 1 fused: A1 fp8, A2 fp8
        g.A1[p] = hp8;
        g.A2[p] = ap8;
        g.Bt[p] = btp + 65536;
        g.bias[p] = prm[p].b1;
      }
    }
    return g;
  };

  const int GX1 = (N_NODES + 127) / 128;        // 391 tiles (MODE 3 grid)
  const int GX2 = (GX1 + 1) / 2;                // 196 blocks, 2 tiles each

  (void)hipMemsetAsync(zbase, 0, zbytes, stream);
  cvt_weightsA<<<(2 * 106496 + 255) / 256, 256, 0, stream>>>(ca);
  // edge partition + CSR build
  part_edges<<<(2 * E_EDGES + 2047) / 2048, 256, 0, stream>>>(ea, sbuf, gcursor);
  build_csr<<<NSB, 512, 0, stream>>>(sbuf, gcursor, offs, dinv, colu);
  cnt_count<<<(TWO_N + 255) / 256, 256, 0, stream>>>(ea, cnt);
  // encode (both panels) + BN stats; h8 stays PRE-BN (affine folded downstream)
  gemm_stream<128, 0, IN_DIM><<<dim3(GX2, 2), 512, 0, stream>>>(mkga(0), N_NODES);
  bn_final<<<1, 256, 0, stream>>>(bnstat, prm[0].bn_g, prm[0].bn_b,
                                  prm[1].bn_g, prm[1].bn_b, abc);
  cvt_fold<<<(65536 + 256 + 255) / 256, 256, 0, stream>>>(
      prm[0].Wl0, prm[0].Wr0, prm[1].Wl0, prm[1].Wr0, prm[0].b0, prm[1].b0,
      abc, BtAll);
  // SAGE layer 0 (fp8 h8 + fp8 agg; writes ONLY h8; deg==0 rows -> nc patch)
  aggregate_fp8<<<(TWO_N * 64 + 255) / 256, 256, 0, stream>>>(
      h8b, colu, offs, dinv, abc + 512, agg8);
  gemm_stream<128, 1, 2 * HID><<<dim3(GX2, 2), 512, 0, stream>>>(mkga(1), N_NODES);
  // SAGE layer 1 + FUSED projection/mean-pool (all-fp8 A; h never materialized)
  aggregate_fp8<<<(TWO_N * 64 + 255) / 256, 256, 0, stream>>>(
      h8b, colu, offs, dinv, zerobuf, agg8);
  gemm_stream<128, 3, 2 * HID><<<dim3(GX1, 2), 512, 0, stream>>>(mkga(3), N_NODES);
  mse_kernel<<<dim3(128, 2), 256, 0, stream>>>(yb, xmat[0], xmat[1], lossacc);
  finalize<<<1, 64, 0, stream>>>(lossacc, (float*)d_out);
}

// Round 19
// 274.507 us; speedup vs baseline: 1.0144x; 1.0144x over previous
//
#include <hip/hip_runtime.h>

#define N_NODES 50000
#define E_EDGES 800000
#define M_ROWS  12500
#define IN_DIM  256
#define HID     128
#define OUT_DIM 64
#define EPS     1e-5f
#define SLOPE   0.1f
#define SB_BITS 9
#define SB_SIZE 512
#define NSB     196         // ceil(2N / 512) super-buckets
#define SB_CAP  (12 * 1024) // mean 8192, sigma~90 -> 45 sigma; fixed inputs safe

typedef unsigned short u16;
typedef unsigned int u32;
typedef unsigned char u8;
typedef __attribute__((ext_vector_type(8))) short short8;
typedef __attribute__((ext_vector_type(4))) float f32x4;
typedef __attribute__((ext_vector_type(2))) float f32x2;
typedef __attribute__((ext_vector_type(2))) unsigned int u32x2;

__device__ __forceinline__ float leaky_f(float x) { return x >= 0.f ? x : SLOPE * x; }

__device__ __forceinline__ u16 f2bf(float f) {
  u32 x = __float_as_uint(f);
  return (u16)((x + 0x7fffu + ((x >> 16) & 1u)) >> 16);
}
__device__ __forceinline__ float bf2f(u16 u) { return __uint_as_float((u32)u << 16); }

// f32 -> OCP e4m3fn, RNE. Max finite 448 (0x7E); clamps NaN/overflow to 448.
__device__ __forceinline__ u8 f2fp8(float f) {
  u32 x = __float_as_uint(f);
  u32 sgn = (x >> 24) & 0x80u;
  u32 ax = x & 0x7fffffffu;
  if (ax > 0x43e00000u) ax = 0x43e00000u;     // clamp |f| to 448
  u32 code;
  if (ax < 0x3c800000u) {                     // |f| < 2^-6: subnormal (n * 2^-9)
    code = (u32)(__uint_as_float(ax) * 512.0f + 0.5f);
  } else {
    u32 rr = ax + 0x7ffffu + ((ax >> 20) & 1u);  // RNE at bit 20
    code = (rr >> 20) - 960u;                    // (e32<<3|m3) - (120<<3)
    if (code > 0x7eu) code = 0x7eu;
  }
  return (u8)(sgn | code);
}

#if defined(__has_builtin)
#if __has_builtin(__builtin_amdgcn_cvt_pk_f32_fp8)
#define HAVE_CVT_FP8 1
#endif
#if __has_builtin(__builtin_amdgcn_cvt_pk_fp8_f32)
#define HAVE_CVT_FP8PK 1
#endif
#endif

#ifdef HAVE_CVT_FP8
template <bool HI>
__device__ __forceinline__ f32x2 fp8pair(u32 w) {
  return __builtin_amdgcn_cvt_pk_f32_fp8((int)w, HI);  // HI is constexpr
}
#else
__device__ __forceinline__ float fp8one(u32 b) {
  u32 em = b & 0x7fu;
  float m = (em >= 8u) ? __uint_as_float((((em >> 3) + 120u) << 23) | ((em & 7u) << 20))
                       : (float)em * (1.f / 512.f);
  return (b & 0x80u) ? -m : m;
}
template <bool HI>
__device__ __forceinline__ f32x2 fp8pair(u32 w) {
  u32 s = HI ? 16 : 0;
  f32x2 r;
  r.x = fp8one((w >> s) & 0xffu);
  r.y = fp8one((w >> (s + 8)) & 0xffu);
  return r;
}
#endif

// pack 2 f32 -> 2 fp8 bytes (low 16 bits). HW packed cvt where available.
__device__ __forceinline__ u32 fp8pk2(float a, float b) {
#ifdef HAVE_CVT_FP8PK
  return ((u32)__builtin_amdgcn_cvt_pk_fp8_f32(a, b, 0, false)) & 0xffffu;
#else
  return (u32)f2fp8(a) | ((u32)f2fp8(b) << 8);
#endif
}

// 8 fp8 (u32x2) -> 8 bf16. LOSSLESS: e4m3 subset of bf16.
__device__ __forceinline__ short8 fp8x8_bf16(u32x2 v) {
  f32x2 p0 = fp8pair<false>(v.x), p1 = fp8pair<true>(v.x);
  f32x2 p2 = fp8pair<false>(v.y), p3 = fp8pair<true>(v.y);
  short8 s;
  s[0] = (short)f2bf(p0.x); s[1] = (short)f2bf(p0.y);
  s[2] = (short)f2bf(p1.x); s[3] = (short)f2bf(p1.y);
  s[4] = (short)f2bf(p2.x); s[5] = (short)f2bf(p2.y);
  s[6] = (short)f2bf(p3.x); s[7] = (short)f2bf(p3.y);
  return s;
}

struct GArgs {
  const void* A1[2];
  const void* A2[2];
  const u16* Bt[2];
  const u16* Bt2[2];    // Wp (fused pool), MODE 3 only
  const float* bias[2];
  const float* bias2[2];// bp (fused pool)
  u8* h8[2];            // fp8 e4m3 activation storage (the ONLY h)
  float* bnsum[2];
  float* bnss[2];
  const int* seg[2];
  const int* cnt[2];
  float* y[2];
};

struct EdgeArgs {
  const int* src[2];
  const int* dst[2];
  const int* seg[2];
};

struct CvtArgs {
  const float* W[12];
  u16* Bt;
};

// ---------------------------------------------------------------------------
// R17-proven streaming MFMA GEMM (278.3us best; R18's 2-tile persistent-B
// REVERTED: it raised GEMM FETCH 50.7->73.4MB and dur 56->66us).
// MODE 0 ENCODE: A1 = f32, K in 2 halves; writes ONLY h8; BN stats f32 exact.
// MODE 1 LAYER0: A1 = fp8 h8, A2 = fp8 agg8; writes ONLY h8.
// MODE 3 LAYER1+POOL: A1/A2 fp8; fused v@Wp + pool atomics (h never stored).
// ---------------------------------------------------------------------------
template <int BN, int MODE, int KTOT>
__global__ __launch_bounds__(512, 4) void gemm_stream(GArgs ga, int nrows) {
  constexpr int NI = BN / 16;
  constexpr int KT = KTOT / 32;
  constexpr int LDK = KTOT + 8;                 // pad 8 u16 = 16B
  constexpr int BEL = BN * KTOT;                // B elements
  constexpr int SIT = BEL / (512 * 8);          // staging iters
  constexpr int KSH = (KTOT == 256) ? 8 : 7;
  __shared__ u16 Bs[BN * LDK];
  __shared__ float redS[(MODE == 0) ? 128 : 1];
  __shared__ float redQ[(MODE == 0) ? 128 : 1];

  const int pb = blockIdx.y;
  const int t = threadIdx.x;
  const int w = t >> 6, lane = t & 63;
  const int laneM = lane & 15, kg = lane >> 4;
  const int r0 = blockIdx.x * 128 + w * 16;

  const u16* Bt = ga.Bt[pb];
  const float* bias = ga.bias[pb];

  int ra = r0 + laneM;
  if (ra >= nrows) ra = nrows - 1;

  short8 sreg[SIT];
  short8 af[KT];

  if constexpr (MODE == 0) {
    const float* A = (const float*)ga.A1[pb] + (size_t)ra * KTOT + kg * 8;
    float4 pf[8];
    // ---- issue B staging + A half-0: one parallel wall ----
#pragma unroll
    for (int si = 0; si < SIT; si++)
      sreg[si] = *(const short8*)(Bt + si * 4096 + t * 8);
#pragma unroll
    for (int kt = 0; kt < 4; kt++) {
      pf[2 * kt] = *(const float4*)(A + kt * 32);
      pf[2 * kt + 1] = *(const float4*)(A + kt * 32 + 4);
    }
    __builtin_amdgcn_sched_barrier(0);
#pragma unroll
    for (int kt = 0; kt < 4; kt++) {
      float4 v0 = pf[2 * kt], v1 = pf[2 * kt + 1];
      short8 s;
      s[0] = (short)f2bf(v0.x); s[1] = (short)f2bf(v0.y);
      s[2] = (short)f2bf(v0.z); s[3] = (short)f2bf(v0.w);
      s[4] = (short)f2bf(v1.x); s[5] = (short)f2bf(v1.y);
      s[6] = (short)f2bf(v1.z); s[7] = (short)f2bf(v1.w);
      af[kt] = s;
    }
    // B -> LDS (vmcnt already drained by the converts)
#pragma unroll
    for (int si = 0; si < SIT; si++) {
      int i = si * 4096 + t * 8;
      *(short8*)&Bs[(i >> KSH) * LDK + (i & (KTOT - 1))] = sreg[si];
    }
    // ---- A half-1 (pf reuse enforces ordering; wall mostly hidden) ----
#pragma unroll
    for (int kt = 0; kt < 4; kt++) {
      pf[2 * kt] = *(const float4*)(A + 128 + kt * 32);
      pf[2 * kt + 1] = *(const float4*)(A + 128 + kt * 32 + 4);
    }
    __builtin_amdgcn_sched_barrier(0);
#pragma unroll
    for (int kt = 0; kt < 4; kt++) {
      float4 v0 = pf[2 * kt], v1 = pf[2 * kt + 1];
      short8 s;
      s[0] = (short)f2bf(v0.x); s[1] = (short)f2bf(v0.y);
      s[2] = (short)f2bf(v0.z); s[3] = (short)f2bf(v0.w);
      s[4] = (short)f2bf(v1.x); s[5] = (short)f2bf(v1.y);
      s[6] = (short)f2bf(v1.z); s[7] = (short)f2bf(v1.w);
      af[4 + kt] = s;
    }
    if (t < 128) { redS[t] = 0.f; redQ[t] = 0.f; }
  } else {
    // ---- B staging + fp8 A1 + fp8 A2: one parallel wall ----
#pragma unroll
    for (int si = 0; si < SIT; si++)
      sreg[si] = *(const short8*)(Bt + si * 4096 + t * 8);
    const u8* A1 = (const u8*)ga.A1[pb] + (size_t)ra * HID + kg * 8;
    const u8* A2 = (const u8*)ga.A2[pb] + (size_t)ra * HID + kg * 8;
    u32x2 a8[8];
#pragma unroll
    for (int kt = 0; kt < 4; kt++) a8[kt] = *(const u32x2*)(A1 + kt * 32);
#pragma unroll
    for (int kt = 0; kt < 4; kt++) a8[4 + kt] = *(const u32x2*)(A2 + kt * 32);
    __builtin_amdgcn_sched_barrier(0);
#pragma unroll
    for (int kt = 0; kt < 8; kt++) af[kt] = fp8x8_bf16(a8[kt]);
    // B -> LDS
#pragma unroll
    for (int si = 0; si < SIT; si++) {
      int i = si * 4096 + t * 8;
      *(short8*)&Bs[(i >> KSH) * LDK + (i & (KTOT - 1))] = sreg[si];
    }
  }
  __syncthreads();

  // ---- steady state: pure LDS + MFMA ----
  f32x4 acc[NI];
#pragma unroll
  for (int ni = 0; ni < NI; ni++) acc[ni] = (f32x4){0.f, 0.f, 0.f, 0.f};

#pragma unroll
  for (int kt = 0; kt < KT; kt++) {
    const int k0 = kt * 32 + kg * 8;
    short8 a = af[kt];
#pragma unroll
    for (int ni = 0; ni < NI; ni++) {
      short8 b = *(const short8*)&Bs[(ni * 16 + laneM) * LDK + k0];
      acc[ni] = __builtin_amdgcn_mfma_f32_16x16x32_bf16(a, b, acc[ni], 0, 0, 0);
    }
  }

  // ---- epilogue ----
  float bcol[NI];
#pragma unroll
  for (int ni = 0; ni < NI; ni++) bcol[ni] = bias[ni * 16 + laneM];

  if constexpr (MODE == 3) {
    // ---- fused projection + mean-pool ----
    u16* Vt = Bs;                   // [128][136] bf16 v-tile (reuses dead Bs)
    u16* Wpt = Bs + 128 * 136;      // [64][136] bf16 Wp
    const u16* Bt2 = ga.Bt2[pb];
    short8 wp[2];
    {
      int i0 = t * 2;               // 1024 short8s of Wp, 2 per thread
      wp[0] = *(const short8*)(Bt2 + (size_t)i0 * 8);
      wp[1] = *(const short8*)(Bt2 + (size_t)(i0 + 1) * 8);
    }
    __syncthreads();                // all waves done reading Bs (W1)
#pragma unroll
    for (int r = 0; r < 4; r++) {
      int lrow = w * 16 + kg * 4 + r;
#pragma unroll
      for (int ni = 0; ni < NI; ni++) {
        float v = leaky_f(acc[ni][r] + bcol[ni]);
        Vt[lrow * 136 + ni * 16 + laneM] = f2bf(v);
      }
    }
    {
      int i0 = t * 2;
#pragma unroll
      for (int q = 0; q < 2; q++) {
        int i = i0 + q;
        *(short8*)&Wpt[(i >> 4) * 136 + (i & 15) * 8] = wp[q];
      }
    }
    __syncthreads();
    f32x4 acc2[4];
#pragma unroll
    for (int n2 = 0; n2 < 4; n2++) acc2[n2] = (f32x4){0.f, 0.f, 0.f, 0.f};
#pragma unroll
    for (int kt = 0; kt < 4; kt++) {
      int k0 = kt * 32 + kg * 8;
      short8 a2 = *(const short8*)&Vt[(w * 16 + laneM) * 136 + k0];
#pragma unroll
      for (int n2 = 0; n2 < 4; n2++) {
        short8 b2 = *(const short8*)&Wpt[(n2 * 16 + laneM) * 136 + k0];
        acc2[n2] = __builtin_amdgcn_mfma_f32_16x16x32_bf16(a2, b2, acc2[n2], 0, 0, 0);
      }
    }
    const float* bp2 = ga.bias2[pb];
#pragma unroll
    for (int r = 0; r < 4; r++) {
      int gr = r0 + kg * 4 + r;
      if (gr >= nrows) continue;
      int sI = ga.seg[pb][gr];
      int cv = ga.cnt[pb][sI];
      float pw = 1.f / (float)(cv > 1 ? cv : 1);
#pragma unroll
      for (int n2 = 0; n2 < 4; n2++) {
        int col = n2 * 16 + laneM;
        float v = acc2[n2][r] + bp2[col];
        atomicAdd(&ga.y[pb][(size_t)sI * OUT_DIM + col], v * pw);
      }
    }
    return;
  }

  float ssum[NI], ssq[NI];
#pragma unroll
  for (int ni = 0; ni < NI; ni++) { ssum[ni] = 0.f; ssq[ni] = 0.f; }

#pragma unroll
  for (int r = 0; r < 4; r++) {
    int gr = r0 + kg * 4 + r;
    if (gr >= nrows) continue;
    float vv[NI];
#pragma unroll
    for (int ni = 0; ni < NI; ni++) {
      float v = leaky_f(acc[ni][r] + bcol[ni]);
      vv[ni] = v;
      if constexpr (MODE == 0) { ssum[ni] += v; ssq[ni] += v * v; }
    }
    u8* hrow = ga.h8[pb] + (size_t)gr * BN + laneM;
#pragma unroll
    for (int ni = 0; ni < NI; ni += 2) {
      u32 pk = fp8pk2(vv[ni], vv[ni + 1]);
      hrow[ni * 16] = (u8)pk;
      hrow[(ni + 1) * 16] = (u8)(pk >> 8);
    }
  }

  if constexpr (MODE == 0) {
#pragma unroll
    for (int ni = 0; ni < NI; ni++) {
      float a = ssum[ni], b = ssq[ni];
      a += __shfl_xor(a, 16); a += __shfl_xor(a, 32);
      b += __shfl_xor(b, 16); b += __shfl_xor(b, 32);
      if (kg == 0) {
        atomicAdd(&redS[ni * 16 + laneM], a);
        atomicAdd(&redQ[ni * 16 + laneM], b);
      }
    }
    __syncthreads();
    if (t < 128) {
      atomicAdd(&ga.bnsum[pb][t], redS[t]);
      atomicAdd(&ga.bnss[pb][t], redQ[t]);
    }
  }
}

// Weights -> bf16 transposed Bt[n][k]; SKIPS Bt0 (folded later with BN affine).
__global__ __launch_bounds__(256) void cvt_weightsA(CvtArgs a) {
  int i = blockIdx.x * 256 + threadIdx.x;
  if (i >= 2 * 106496) return;
  int p = i >= 106496;
  int j = i - p * 106496;
  const float* const* W = a.W + p * 6;
  u16* out = a.Bt + (size_t)p * 106496;
  if (j < 32768) {
    int n = j >> 8, k = j & 255;
    out[j] = f2bf(W[0][k * 128 + n]);
  } else if (j < 65536) {
    return;
  } else if (j < 98304) {
    int q = j - 65536, n = q >> 8, k = q & 255;
    out[j] = f2bf(k < 128 ? W[3][k * 128 + n] : W[4][(k - 128) * 128 + n]);
  } else {
    int q = j - 98304, n = q >> 7, k = q & 127;
    out[j] = f2bf(W[5][k * 64 + n]);
  }
}

// abc layout: a[256] | c[256] | nc[256] | bias0p[256]
__global__ void bn_final(const float* __restrict__ bnstat,
                         const float* __restrict__ g0, const float* __restrict__ b0,
                         const float* __restrict__ g1, const float* __restrict__ b1,
                         float* __restrict__ abc) {
  int t = threadIdx.x;  // 256
  int p = t >> 7, cix = t & 127;
  const float* bs = bnstat + p * 256;
  float mu = bs[cix] * (1.f / N_NODES);
  float var = bs[128 + cix] * (1.f / N_NODES) - mu * mu;
  float rs = rsqrtf(var + EPS);
  const float* g = p ? g1 : g0;
  const float* b = p ? b1 : b0;
  float av = g[cix] * rs;
  float cv = b[cix] - mu * av;
  abc[t] = av;
  abc[256 + t] = cv;
  abc[512 + t] = (av != 0.f) ? (-cv / av) : 0.f;
}

// Fold BN affine into layer-0 weights.
__global__ __launch_bounds__(256) void cvt_fold(
    const float* __restrict__ Wl0_0, const float* __restrict__ Wr0_0,
    const float* __restrict__ Wl0_1, const float* __restrict__ Wr0_1,
    const float* __restrict__ b0_0, const float* __restrict__ b0_1,
    float* __restrict__ abc, u16* __restrict__ BtAll) {
  int i = blockIdx.x * 256 + threadIdx.x;
  if (i < 65536) {
    int p = i >> 15, q = i & 32767;
    int n = q >> 8, k = q & 255;
    const float* Wl = p ? Wl0_1 : Wl0_0;
    const float* Wr = p ? Wr0_1 : Wr0_0;
    float wv = (k < 128) ? Wl[k * 128 + n] : Wr[(k - 128) * 128 + n];
    float av = abc[p * 128 + (k & 127)];
    BtAll[(size_t)p * 106496 + 32768 + q] = f2bf(wv * av);
  } else if (i < 65536 + 256) {
    int j = i - 65536;
    int p = j >> 7, n = j & 127;
    const float* Wl = p ? Wl0_1 : Wl0_0;
    const float* Wr = p ? Wr0_1 : Wr0_0;
    const float* c = abc + 256 + p * 128;
    float s = (p ? b0_1 : b0_0)[n];
    for (int k = 0; k < 128; k++) s += c[k] * (Wl[k * 128 + n] + Wr[k * 128 + n]);
    abc[768 + j] = s;
  }
}

// --------- Phase A: partition edges into NSB super-buckets ------------------
// packed: dst_local(9b) << 17 | src(16b). Tile = 2048 edges, block-local
// counting sort, wave-per-bucket chunk copy-out.
__global__ __launch_bounds__(256) void part_edges(EdgeArgs ea, u32* __restrict__ sbuf,
                                                  int* __restrict__ gcursor) {
  __shared__ u32 lpack[2048];
  __shared__ int hist[NSB], base[NSB], gbase[NSB], lofs[NSB];
  int t = threadIdx.x;
  int e0 = blockIdx.x * 2048;
  for (int i = t; i < NSB; i += 256) hist[i] = 0;
  __syncthreads();
  u32 myp[8];
  int myb[8];
#pragma unroll
  for (int q = 0; q < 8; q++) {
    int i = e0 + q * 256 + t;
    int b = -1;
    u32 pk = 0;
    if (i < 2 * E_EDGES) {
      int p = i >= E_EDGES;
      int j = i - p * E_EDGES;
      int d = p * N_NODES + ea.dst[p][j];
      int s = ea.src[p][j];
      b = d >> SB_BITS;
      pk = ((u32)(d & (SB_SIZE - 1)) << 17) | (u32)s;
      atomicAdd(&hist[b], 1);
    }
    myb[q] = b;
    myp[q] = pk;
  }
  __syncthreads();
  if (t == 0) {
    int acc = 0;
    for (int b = 0; b < NSB; b++) { base[b] = acc; acc += hist[b]; }
  }
  __syncthreads();
  for (int i = t; i < NSB; i += 256) {
    lofs[i] = 0;
    gbase[i] = atomicAdd(&gcursor[i], hist[i]);
  }
  __syncthreads();
#pragma unroll
  for (int q = 0; q < 8; q++) {
    if (myb[q] >= 0) {
      int pos = atomicAdd(&lofs[myb[q]], 1);
      lpack[base[myb[q]] + pos] = myp[q];
    }
  }
  __syncthreads();
  int wid = t >> 6, lane = t & 63;
  for (int b = wid; b < NSB; b += 4) {
    int n = hist[b], lb = base[b], gb = gbase[b];
    for (int k = lane; k < n; k += 64)
      sbuf[(size_t)b * SB_CAP + gb + k] = lpack[lb + k];
  }
}

// --------- Phase B: per-super-bucket CSR build (one block per bucket) -------
// 196 blocks x 512 threads; ~8K edges/block. R19: also folds the pooling
// cnt_count here (each node visited exactly once) -- kills one dispatch.
__global__ __launch_bounds__(512) void build_csr(
    const u32* __restrict__ sbuf, const int* __restrict__ gtot,
    int* __restrict__ offs, float* __restrict__ dinv, u16* __restrict__ colu,
    const int* __restrict__ seg0, const int* __restrict__ seg1,
    int* __restrict__ cnt) {
  __shared__ int ldeg[SB_SIZE];
  __shared__ int lcur[SB_SIZE];
  __shared__ int wsum[8];
  __shared__ int sbase_s;
  int b = blockIdx.x, t = threadIdx.x;
  int lane = t & 63, wid = t >> 6;
  ldeg[t] = 0;
  if (t < 64) {
    // edge_base = sum of gtot[0..b) via 64-lane masked sum + butterfly
    int s = 0;
    for (int i = lane; i < b; i += 64) s += gtot[i];
#pragma unroll
    for (int off = 1; off < 64; off <<= 1) s += __shfl_xor(s, off, 64);
    if (lane == 0) sbase_s = s;
  }
  __syncthreads();
  const int cntE = gtot[b];
  const int edge_base = sbase_s;
  const int node0 = b << SB_BITS;
  int nend = 2 * N_NODES - node0;
  if (nend > SB_SIZE) nend = SB_SIZE;
  const u32* me = sbuf + (size_t)b * SB_CAP;
  for (int k = t; k < cntE; k += 512) atomicAdd(&ldeg[me[k] >> 17], 1);
  // fused pooling count for this bucket's nodes (independent of ldeg)
  if (t < nend) {
    int n = node0 + t;
    int p = n >= N_NODES;
    int k = n - p * N_NODES;
    atomicAdd(&cnt[p * M_ROWS + (p ? seg1 : seg0)[k]], 1);
  }
  __syncthreads();
  // block scan over 512 (one node per thread)
  int d = ldeg[t];
  int incl = d;
#pragma unroll
  for (int off = 1; off < 64; off <<= 1) {
    int u = __shfl_up(incl, off, 64);
    if (lane >= off) incl += u;
  }
  if (lane == 63) wsum[wid] = incl;
  __syncthreads();
  if (t == 0) {
    int acc = 0;
#pragma unroll
    for (int i = 0; i < 8; i++) { int v = wsum[i]; wsum[i] = acc; acc += v; }
  }
  __syncthreads();
  int ex = wsum[wid] + incl - d;
  if (t < nend) {
    offs[node0 + t] = edge_base + ex;
    dinv[node0 + t] = d > 0 ? 1.f / (float)d : -1.f;
  }
  lcur[t] = ex;
  __syncthreads();
  for (int k = t; k < cntE; k += 512) {
    u32 v = me[k];
    int pos = atomicAdd(&lcur[v >> 17], 1);
    colu[edge_base + pos] = (u16)(v & 0xFFFFu);
  }
  if (b == 0 && t == 0) offs[2 * N_NODES] = 2 * E_EDGES;
}

// --------- mean-aggregate: fp8 gather, fp8 output ---------------------------
// 1 wave/node, 4 edge-groups x 16 col-lanes; lane loads uint2 (8B = 8 fp8
// cols, 2 lines/edge) -- the empirically optimal shape. Output agg8 fp8 via
// packed cvt (R12-validated). dinv<0 marks deg==0 -> nc[col] (f32).
__global__ __launch_bounds__(256) void aggregate_fp8(
    const u8* __restrict__ h8, const u16* __restrict__ colu,
    const int* __restrict__ offs, const float* __restrict__ dinv,
    const float* __restrict__ nc, u8* __restrict__ agg) {
  int gw = (blockIdx.x * 256 + threadIdx.x) >> 6;
  int lane = threadIdx.x & 63;
  if (gw >= 2 * N_NODES) return;
  int panel = gw >= N_NODES;
  const uint2* hp = (const uint2*)(h8 + (size_t)panel * N_NODES * 128);
  int grp = lane >> 4, li = lane & 15;
  int s = offs[gw], e = offs[gw + 1];
  float a[8];
#pragma unroll
  for (int k = 0; k < 8; k++) a[k] = 0.f;

  auto acc8 = [&](uint2 v) {
    f32x2 p0 = fp8pair<false>(v.x);
    f32x2 p1 = fp8pair<true>(v.x);
    f32x2 p2 = fp8pair<false>(v.y);
    f32x2 p3 = fp8pair<true>(v.y);
    a[0] += p0.x; a[1] += p0.y; a[2] += p1.x; a[3] += p1.y;
    a[4] += p2.x; a[5] += p2.y; a[6] += p3.x; a[7] += p3.y;
  };

  int j = s;
  for (; j + 16 <= e; j += 16) {
    int c0 = colu[j + grp];
    int c1 = colu[j + 4 + grp];
    int c2 = colu[j + 8 + grp];
    int c3 = colu[j + 12 + grp];
    uint2 v0 = hp[(size_t)c0 * 16 + li];
    uint2 v1 = hp[(size_t)c1 * 16 + li];
    uint2 v2 = hp[(size_t)c2 * 16 + li];
    uint2 v3 = hp[(size_t)c3 * 16 + li];
    acc8(v0); acc8(v1); acc8(v2); acc8(v3);
  }
  for (; j + 4 <= e; j += 4) {
    int c = colu[j + grp];
    uint2 v = hp[(size_t)c * 16 + li];
    acc8(v);
  }
  if (j + grp < e) {
    int c = colu[j + grp];
    uint2 v = hp[(size_t)c * 16 + li];
    acc8(v);
  }

#pragma unroll
  for (int k = 0; k < 8; k++) {
    a[k] += __shfl_xor(a[k], 16);
    a[k] += __shfl_xor(a[k], 32);
  }

  if (grp == 0) {
    float di = dinv[gw];
    float o[8];
    if (di < 0.f) {
      const float* np = nc + panel * 128 + li * 8;
#pragma unroll
      for (int k = 0; k < 8; k++) o[k] = np[k];
    } else {
#pragma unroll
      for (int k = 0; k < 8; k++) o[k] = a[k] * di;
    }
    uint2 ov;
    ov.x = fp8pk2(o[0], o[1]) | (fp8pk2(o[2], o[3]) << 16);
    ov.y = fp8pk2(o[4], o[5]) | (fp8pk2(o[6], o[7]) << 16);
    ((uint2*)agg)[(size_t)gw * 16 + li] = ov;
  }
}

__global__ __launch_bounds__(256) void mse_kernel(const float* __restrict__ yb,
                                                  const float* __restrict__ x0,
                                                  const float* __restrict__ x1,
                                                  float* __restrict__ acc) {
  __shared__ float ls[256];
  int pb = blockIdx.y;
  const float* y = yb + (size_t)pb * M_ROWS * OUT_DIM;
  const float* x = pb ? x1 : x0;
  float s = 0.f;
  for (int i = blockIdx.x * 256 + threadIdx.x; i < M_ROWS * OUT_DIM; i += gridDim.x * 256) {
    float d = y[i] - x[i];
    s += d * d;
  }
  ls[threadIdx.x] = s;
  __syncthreads();
  for (int o = 128; o > 0; o >>= 1) {
    if (threadIdx.x < o) ls[threadIdx.x] += ls[threadIdx.x + o];
    __syncthreads();
  }
  if (threadIdx.x == 0) atomicAdd(&acc[pb], ls[0]);
}

__global__ void finalize(const float* __restrict__ acc, float* __restrict__ out) {
  int t = threadIdx.x;
  if (t < 2) out[t] = acc[t] * (1.f / (float)(M_ROWS * OUT_DIM));
}

// ---------------------------------------------------------------------------
extern "C" void kernel_launch(void* const* d_in, const int* in_sizes, int n_in,
                              void* d_out, int out_size, void* d_ws, size_t ws_size,
                              hipStream_t stream) {
  (void)in_sizes; (void)n_in; (void)out_size; (void)ws_size;
  const float* feat[2] = {(const float*)d_in[0], (const float*)d_in[1]};
  const float* xmat[2] = {(const float*)d_in[2], (const float*)d_in[3]};
  const int* esrc[2] = {(const int*)d_in[4], (const int*)d_in[6]};
  const int* edst[2] = {(const int*)d_in[5], (const int*)d_in[7]};
  const int* aseg[2] = {(const int*)d_in[8], (const int*)d_in[9]};

  struct P {
    const float *W_mlp, *b_mlp, *bn_g, *bn_b, *Wl0, *Wr0, *b0, *Wl1, *Wr1, *b1, *Wp, *bp;
  } prm[2];
  for (int p = 0; p < 2; p++) {
    int b = 10 + 12 * p;
    prm[p] = {(const float*)d_in[b + 0], (const float*)d_in[b + 1],
              (const float*)d_in[b + 2], (const float*)d_in[b + 3],
              (const float*)d_in[b + 4], (const float*)d_in[b + 5],
              (const float*)d_in[b + 6], (const float*)d_in[b + 7],
              (const float*)d_in[b + 8], (const float*)d_in[b + 9],
              (const float*)d_in[b + 10], (const float*)d_in[b + 11]};
  }

  char* w = (char*)d_ws;
  auto carve = [&](size_t bytes) -> char* {
    char* r = w;
    w += (bytes + 255) & ~(size_t)255;
    return r;
  };
  // ---- zeroed region (single memset) ----
  char* zbase = w;
  int* gcursor = (int*)carve(NSB * 4);
  int* cnt    = (int*)carve((size_t)2 * M_ROWS * 4);
  float* bnstat = (float*)carve(2 * 256 * 4);
  float* lossacc = (float*)carve(64 * 4);
  float* zerobuf = (float*)carve(256 * 4);
  float* yb   = (float*)carve((size_t)2 * M_ROWS * OUT_DIM * 4);
  size_t zbytes = (size_t)(w - zbase);
  // ---- non-zeroed ----
  u8* agg8  = (u8*)carve((size_t)2 * N_NODES * HID);       // fp8 agg (12.8MB)
  u32* sbuf = (u32*)agg8;  // aliased: sbuf (9.4MB) dead before first aggregate write
  u8* h8b   = (u8*)carve((size_t)2 * N_NODES * HID);       // fp8 h (only h storage)
  float* dinv = (float*)carve((size_t)2 * N_NODES * 4);
  float* abc = (float*)carve(1024 * 4);  // a|c|nc|bias0p
  int* offs = (int*)carve((size_t)(2 * N_NODES + 1) * 4);
  u16* colu = (u16*)carve((size_t)2 * E_EDGES * 2);
  u16* BtAll = (u16*)carve((size_t)2 * 106496 * 2);

  const int TWO_N = 2 * N_NODES;

  EdgeArgs ea;
  for (int p = 0; p < 2; p++) { ea.src[p] = esrc[p]; ea.dst[p] = edst[p]; ea.seg[p] = aseg[p]; }

  CvtArgs ca;
  for (int p = 0; p < 2; p++) {
    ca.W[p * 6 + 0] = prm[p].W_mlp; ca.W[p * 6 + 1] = prm[p].Wl0;
    ca.W[p * 6 + 2] = prm[p].Wr0;   ca.W[p * 6 + 3] = prm[p].Wl1;
    ca.W[p * 6 + 4] = prm[p].Wr1;   ca.W[p * 6 + 5] = prm[p].Wp;
  }
  ca.Bt = BtAll;

  auto mkga = [&](int mode) {
    GArgs g{};
    for (int p = 0; p < 2; p++) {
      u8* hp8 = h8b + (size_t)p * N_NODES * HID;
      u8* ap8 = agg8 + (size_t)p * N_NODES * HID;
      const u16* btp = BtAll + (size_t)p * 106496;
      g.h8[p] = hp8;
      g.bnsum[p] = bnstat + p * 256;
      g.bnss[p] = bnstat + p * 256 + 128;
      g.seg[p] = aseg[p];
      g.cnt[p] = cnt + p * M_ROWS;
      g.y[p] = yb + (size_t)p * M_ROWS * OUT_DIM;
      g.Bt2[p] = btp + 98304;
      g.bias2[p] = prm[p].bp;
      if (mode == 0) {
        g.A1[p] = feat[p];
        g.Bt[p] = btp;
        g.bias[p] = prm[p].b_mlp;
      } else if (mode == 1) {       // layer 0: A1 fp8 h8, A2 fp8 agg8
        g.A1[p] = hp8;
        g.A2[p] = ap8;
        g.Bt[p] = btp + 32768;
        g.bias[p] = (const float*)(abc + 768 + p * 128);
      } else {                      // layer 1 fused: A1 fp8, A2 fp8
        g.A1[p] = hp8;
        g.A2[p] = ap8;
        g.Bt[p] = btp + 65536;
        g.bias[p] = prm[p].b1;
      }
    }
    return g;
  };

  const int GX = (N_NODES + 127) / 128;  // 391 blocks of 128 rows (8 waves x 16)

  (void)hipMemsetAsync(zbase, 0, zbytes, stream);
  cvt_weightsA<<<(2 * 106496 + 255) / 256, 256, 0, stream>>>(ca);
  // edge partition + CSR build (pool counts fused into build_csr)
  part_edges<<<(2 * E_EDGES + 2047) / 2048, 256, 0, stream>>>(ea, sbuf, gcursor);
  build_csr<<<NSB, 512, 0, stream>>>(sbuf, gcursor, offs, dinv, colu,
                                     aseg[0], aseg[1], cnt);
  // encode (both panels) + BN stats; h8 stays PRE-BN (affine folded downstream)
  gemm_stream<128, 0, IN_DIM><<<dim3(GX, 2), 512, 0, stream>>>(mkga(0), N_NODES);
  bn_final<<<1, 256, 0, stream>>>(bnstat, prm[0].bn_g, prm[0].bn_b,
                                  prm[1].bn_g, prm[1].bn_b, abc);
  cvt_fold<<<(65536 + 256 + 255) / 256, 256, 0, stream>>>(
      prm[0].Wl0, prm[0].Wr0, prm[1].Wl0, prm[1].Wr0, prm[0].b0, prm[1].b0,
      abc, BtAll);
  // SAGE layer 0 (fp8 h8 + fp8 agg; writes ONLY h8; deg==0 rows -> nc patch)
  aggregate_fp8<<<(TWO_N * 64 + 255) / 256, 256, 0, stream>>>(
      h8b, colu, offs, dinv, abc + 512, agg8);
  gemm_stream<128, 1, 2 * HID><<<dim3(GX, 2), 512, 0, stream>>>(mkga(1), N_NODES);
  // SAGE layer 1 + FUSED projection/mean-pool (all-fp8 A; h never materialized)
  aggregate_fp8<<<(TWO_N * 64 + 255) / 256, 256, 0, stream>>>(
      h8b, colu, offs, dinv, zerobuf, agg8);
  gemm_stream<128, 3, 2 * HID><<<dim3(GX, 2), 512, 0, stream>>>(mkga(3), N_NODES);
  mse_kernel<<<dim3(128, 2), 256, 0, stream>>>(yb, xmat[0], xmat[1], lossacc);
  finalize<<<1, 64, 0, stream>>>(lossacc, (float*)d_out);
}